// Round 9
// baseline (853.479 us; speedup 1.0000x reference)
//
#include <hip/hip_runtime.h>

#define D 128
#define NB 32          // nodes per bucket
#define LOG_NB 5

typedef short  bf16x8 __attribute__((ext_vector_type(8)));
typedef float  f32x4  __attribute__((ext_vector_type(4)));

// round-to-nearest-even float -> bf16 bits
static __device__ __forceinline__ unsigned short f2bf(float f) {
    unsigned u = __float_as_uint(f);
    u += 0x7FFFu + ((u >> 16) & 1u);
    return (unsigned short)(u >> 16);
}
static __device__ __forceinline__ float bf2f_lo(unsigned u) {
    return __uint_as_float((u & 0xFFFFu) << 16);
}
static __device__ __forceinline__ float bf2f_hi(unsigned u) {
    return __uint_as_float(u & 0xFFFF0000u);
}

// ------------------------------------------- fused: bucket-hist + convert_W
__global__ __launch_bounds__(256) void fused_pre(
    const int* __restrict__ rows, int* __restrict__ bcounts, int n_edges,
    const float* __restrict__ W, unsigned short* __restrict__ Wb, int histBlocks) {
    int bid = blockIdx.x;
    if (bid < histBlocks) {
        int i = bid * 256 + threadIdx.x;
        if (i < n_edges) atomicAdd(&bcounts[rows[i] >> LOG_NB], 1);
    } else {
        int i = (bid - histBlocks) * 256 + threadIdx.x;
        if (i < D * D) Wb[i] = f2bf(W[i]);
    }
}

// ------------------------------------------- single-block scan over buckets
// nb <= 2048 (2 elements per thread). Writes boffs[0..nb] and bcursor copy.
__global__ __launch_bounds__(1024) void scan_buckets(
    const int* __restrict__ bcounts, int* __restrict__ boffs,
    int* __restrict__ bcursor, int nb) {
    __shared__ int sh[1024];
    const int t = threadIdx.x;
    int c0 = (t * 2     < nb) ? bcounts[t * 2]     : 0;
    int c1 = (t * 2 + 1 < nb) ? bcounts[t * 2 + 1] : 0;
    sh[t] = c0 + c1;
    __syncthreads();
    for (int off = 1; off < 1024; off <<= 1) {
        int add = (t >= off) ? sh[t - off] : 0;
        __syncthreads();
        sh[t] += add;
        __syncthreads();
    }
    int base = sh[t] - (c0 + c1);          // exclusive prefix of this pair
    if (t * 2 < nb)     { boffs[t * 2]     = base;      bcursor[t * 2]     = base; }
    if (t * 2 + 1 < nb) { boffs[t * 2 + 1] = base + c0; bcursor[t * 2 + 1] = base + c0; }
    if (t == 1023) boffs[nb] = sh[1023];
}

// ------------------------------------------- fused: bucket-permute + MFMA GEMM
// Even blocks: gemm (16-row x 128-col tile per wave, loads hoisted).
// Odd blocks: grid-stride bucket permute (1563 L2-hot write frontiers,
// ~no line-level write amplification vs per-node scatter).
__global__ __launch_bounds__(256, 4) void fused_main(
    const int* __restrict__ rows, const int* __restrict__ cols,
    const float* __restrict__ vals, int* __restrict__ bcursor,
    int2* __restrict__ evec, int n_edges, int permSlots,
    const float* __restrict__ x, const unsigned short* __restrict__ Wb,
    const float* __restrict__ b, unsigned short* __restrict__ hb, int n_rows) {
    const int bid = blockIdx.x;

    if (bid & 1) {
        const int slot   = bid >> 1;
        const int stride = permSlots * 256;
        for (int i = slot * 256 + threadIdx.x; i < n_edges; i += stride) {
            int r   = rows[i];
            int pos = atomicAdd(&bcursor[r >> LOG_NB], 1);
            unsigned meta = (unsigned)cols[i] | ((unsigned)(r & (NB - 1)) << 16);
            evec[pos] = make_int2((int)meta, __float_as_int(vals[i]));
        }
        return;
    }

    // ---- gemm: h[m][o] = sum_k x[m][k]*W[o][k] + b[o] -> bf16
    const int gb   = bid >> 1;
    const int lane = threadIdx.x & 63;
    const int wv   = threadIdx.x >> 6;
    const int row0 = gb * 64 + wv * 16;
    if (row0 >= n_rows) return;
    const int m  = lane & 15;
    const int kg = lane >> 4;                 // 0..3

    int arow = row0 + m;
    if (arow >= n_rows) arow = n_rows - 1;    // clamp: loads valid, stores predicated
    const float* xr = x + (size_t)arow * D + kg * 8;

    // Load ALL x fragments first (independent; 32 VGPR), then convert, then MFMA.
    float4 xf[8];
#pragma unroll
    for (int ks = 0; ks < 4; ++ks) {
        xf[2 * ks]     = *(const float4*)(xr + ks * 32);
        xf[2 * ks + 1] = *(const float4*)(xr + ks * 32 + 4);
    }
    bf16x8 afr[4];
#pragma unroll
    for (int ks = 0; ks < 4; ++ks) {
        float4 f0 = xf[2 * ks], f1 = xf[2 * ks + 1];
        bf16x8 a;
        a[0] = (short)f2bf(f0.x); a[1] = (short)f2bf(f0.y);
        a[2] = (short)f2bf(f0.z); a[3] = (short)f2bf(f0.w);
        a[4] = (short)f2bf(f1.x); a[5] = (short)f2bf(f1.y);
        a[6] = (short)f2bf(f1.z); a[7] = (short)f2bf(f1.w);
        afr[ks] = a;
    }

    f32x4 acc[8];
#pragma unroll
    for (int n = 0; n < 8; ++n) acc[n] = (f32x4){0.f, 0.f, 0.f, 0.f};

#pragma unroll
    for (int ks = 0; ks < 4; ++ks) {
#pragma unroll
        for (int n = 0; n < 8; ++n) {
            bf16x8 bf = *(const bf16x8*)&Wb[(size_t)(n * 16 + m) * D + ks * 32 + kg * 8];
            acc[n] = __builtin_amdgcn_mfma_f32_16x16x32_bf16(afr[ks], bf, acc[n], 0, 0, 0);
        }
    }

#pragma unroll
    for (int n = 0; n < 8; ++n) {
        int col = n * 16 + m;
        float bc = b[col];
#pragma unroll
        for (int j = 0; j < 4; ++j) {
            int rr = row0 + kg * 4 + j;
            if (rr < n_rows) hb[(size_t)rr * D + col] = f2bf(acc[n][j] + bc);
        }
    }
}

// ------------------------------------------- aggregate: LDS accumulator/bucket
// One block per bucket of 32 nodes. 16 KB LDS acc[32][128] fp32.
// Records unsorted within bucket -> LDS atomicAdd (lane*2 cols: 2-way bank
// aliasing = free). Gathers 8-deep for MLP. Final coalesced float4 store.
__global__ __launch_bounds__(256, 4) void aggregate_lds(
    const int* __restrict__ boffs, const int2* __restrict__ evec,
    const unsigned short* __restrict__ hb, float* __restrict__ out, int n_nodes) {
    __shared__ float acc[NB * D];
    const int t    = threadIdx.x;
    const int lane = t & 63;
    const int wv   = t >> 6;
    const int bkt  = blockIdx.x;

#pragma unroll
    for (int i = t; i < NB * D; i += 256) acc[i] = 0.f;
    __syncthreads();

    const int s = boffs[bkt];
    const int e = boffs[bkt + 1];
    const int cnt   = e - s;
    const int chunk = (cnt + 3) >> 2;
    int k  = s + wv * chunk;
    int ke = min(k + chunk, e);
    const int c0 = lane * 2;

#define DO_REC(MET, VAL)                                                     \
    {                                                                        \
        unsigned _m = (unsigned)(MET);                                       \
        int   _col = (int)(_m & 0xFFFFu);                                    \
        int   _lr  = (int)(_m >> 16);                                        \
        float _v   = __int_as_float(VAL);                                    \
        unsigned _u = *(const unsigned*)&hb[(size_t)_col * D + c0];          \
        atomicAdd(&acc[_lr * D + c0],     _v * bf2f_lo(_u));                 \
        atomicAdd(&acc[_lr * D + c0 + 1], _v * bf2f_hi(_u));                 \
    }

    if ((k & 1) && k < ke) {
        int2 r = evec[k];
        DO_REC(r.x, r.y);
        ++k;
    }
    for (; k + 7 < ke; k += 8) {
        int4 p0 = *(const int4*)&evec[k];
        int4 p1 = *(const int4*)&evec[k + 2];
        int4 p2 = *(const int4*)&evec[k + 4];
        int4 p3 = *(const int4*)&evec[k + 6];
        unsigned m0 = (unsigned)p0.x, m1 = (unsigned)p0.z;
        unsigned m2 = (unsigned)p1.x, m3 = (unsigned)p1.z;
        unsigned m4 = (unsigned)p2.x, m5 = (unsigned)p2.z;
        unsigned m6 = (unsigned)p3.x, m7 = (unsigned)p3.z;
        unsigned u0 = *(const unsigned*)&hb[(size_t)(m0 & 0xFFFFu) * D + c0];
        unsigned u1 = *(const unsigned*)&hb[(size_t)(m1 & 0xFFFFu) * D + c0];
        unsigned u2 = *(const unsigned*)&hb[(size_t)(m2 & 0xFFFFu) * D + c0];
        unsigned u3 = *(const unsigned*)&hb[(size_t)(m3 & 0xFFFFu) * D + c0];
        unsigned u4 = *(const unsigned*)&hb[(size_t)(m4 & 0xFFFFu) * D + c0];
        unsigned u5 = *(const unsigned*)&hb[(size_t)(m5 & 0xFFFFu) * D + c0];
        unsigned u6 = *(const unsigned*)&hb[(size_t)(m6 & 0xFFFFu) * D + c0];
        unsigned u7 = *(const unsigned*)&hb[(size_t)(m7 & 0xFFFFu) * D + c0];
        float v0 = __int_as_float(p0.y), v1 = __int_as_float(p0.w);
        float v2 = __int_as_float(p1.y), v3 = __int_as_float(p1.w);
        float v4 = __int_as_float(p2.y), v5 = __int_as_float(p2.w);
        float v6 = __int_as_float(p3.y), v7 = __int_as_float(p3.w);
        atomicAdd(&acc[(int)(m0 >> 16) * D + c0],     v0 * bf2f_lo(u0));
        atomicAdd(&acc[(int)(m0 >> 16) * D + c0 + 1], v0 * bf2f_hi(u0));
        atomicAdd(&acc[(int)(m1 >> 16) * D + c0],     v1 * bf2f_lo(u1));
        atomicAdd(&acc[(int)(m1 >> 16) * D + c0 + 1], v1 * bf2f_hi(u1));
        atomicAdd(&acc[(int)(m2 >> 16) * D + c0],     v2 * bf2f_lo(u2));
        atomicAdd(&acc[(int)(m2 >> 16) * D + c0 + 1], v2 * bf2f_hi(u2));
        atomicAdd(&acc[(int)(m3 >> 16) * D + c0],     v3 * bf2f_lo(u3));
        atomicAdd(&acc[(int)(m3 >> 16) * D + c0 + 1], v3 * bf2f_hi(u3));
        atomicAdd(&acc[(int)(m4 >> 16) * D + c0],     v4 * bf2f_lo(u4));
        atomicAdd(&acc[(int)(m4 >> 16) * D + c0 + 1], v4 * bf2f_hi(u4));
        atomicAdd(&acc[(int)(m5 >> 16) * D + c0],     v5 * bf2f_lo(u5));
        atomicAdd(&acc[(int)(m5 >> 16) * D + c0 + 1], v5 * bf2f_hi(u5));
        atomicAdd(&acc[(int)(m6 >> 16) * D + c0],     v6 * bf2f_lo(u6));
        atomicAdd(&acc[(int)(m6 >> 16) * D + c0 + 1], v6 * bf2f_hi(u6));
        atomicAdd(&acc[(int)(m7 >> 16) * D + c0],     v7 * bf2f_lo(u7));
        atomicAdd(&acc[(int)(m7 >> 16) * D + c0 + 1], v7 * bf2f_hi(u7));
    }
    for (; k + 1 < ke; k += 2) {
        int4 p0 = *(const int4*)&evec[k];
        DO_REC(p0.x, p0.y);
        DO_REC(p0.z, p0.w);
    }
    if (k < ke) {
        int2 r = evec[k];
        DO_REC(r.x, r.y);
    }
#undef DO_REC

    __syncthreads();
    // write bucket tile: 32 rows x 128 cols = 1024 float4s, coalesced
    const int base = bkt * NB;
    for (int i = t; i < NB * (D / 4); i += 256) {
        int r  = i >> 5;            // / (D/4)
        int cq = i & 31;
        int row = base + r;
        if (row < n_nodes)
            *(float4*)&out[(size_t)row * D + cq * 4] = *(const float4*)&acc[r * D + cq * 4];
    }
}

// ---------------------------------------------------------------- fallback path
__global__ void convert_W(const float* __restrict__ W, unsigned short* __restrict__ Wb) {
    int i = blockIdx.x * blockDim.x + threadIdx.x;
    if (i < D * D) Wb[i] = f2bf(W[i]);
}

__global__ __launch_bounds__(256) void gemm_mfma(
    const float* __restrict__ x, const unsigned short* __restrict__ Wb,
    const float* __restrict__ b, unsigned short* __restrict__ hb, int n_rows) {
    const int lane = threadIdx.x & 63;
    const int wv   = threadIdx.x >> 6;
    const int row0 = blockIdx.x * 64 + wv * 16;
    if (row0 >= n_rows) return;
    const int m  = lane & 15;
    const int kg = lane >> 4;
    int arow = row0 + m;
    if (arow >= n_rows) arow = n_rows - 1;
    const float* xr = x + (size_t)arow * D + kg * 8;
    f32x4 acc[8];
#pragma unroll
    for (int n = 0; n < 8; ++n) acc[n] = (f32x4){0.f, 0.f, 0.f, 0.f};
#pragma unroll
    for (int ks = 0; ks < 4; ++ks) {
        float4 f0 = *(const float4*)(xr + ks * 32);
        float4 f1 = *(const float4*)(xr + ks * 32 + 4);
        bf16x8 a;
        a[0] = (short)f2bf(f0.x); a[1] = (short)f2bf(f0.y);
        a[2] = (short)f2bf(f0.z); a[3] = (short)f2bf(f0.w);
        a[4] = (short)f2bf(f1.x); a[5] = (short)f2bf(f1.y);
        a[6] = (short)f2bf(f1.z); a[7] = (short)f2bf(f1.w);
#pragma unroll
        for (int n = 0; n < 8; ++n) {
            bf16x8 bf = *(const bf16x8*)&Wb[(size_t)(n * 16 + m) * D + ks * 32 + kg * 8];
            acc[n] = __builtin_amdgcn_mfma_f32_16x16x32_bf16(a, bf, acc[n], 0, 0, 0);
        }
    }
#pragma unroll
    for (int n = 0; n < 8; ++n) {
        int col = n * 16 + m;
        float bc = b[col];
#pragma unroll
        for (int j = 0; j < 4; ++j) {
            int r = row0 + kg * 4 + j;
            if (r < n_rows) hb[(size_t)r * D + col] = f2bf(acc[n][j] + bc);
        }
    }
}

__global__ __launch_bounds__(256) void scatter_add(
    const int* __restrict__ rows, const int* __restrict__ cols,
    const float* __restrict__ vals, const unsigned short* __restrict__ hb,
    float* __restrict__ out, int n_edges) {
    long long gid = (long long)blockIdx.x * blockDim.x + threadIdx.x;
    int e  = (int)(gid >> 5);
    if (e >= n_edges) return;
    int d4 = ((int)gid & 31) * 4;
    int   r = rows[e];
    int   c = cols[e];
    float v = vals[e];
    const unsigned short* hp = &hb[(size_t)c * D + d4];
    unsigned u0 = *(const unsigned*)(hp + 0);
    unsigned u1 = *(const unsigned*)(hp + 2);
    float* op = &out[(size_t)r * D + d4];
    atomicAdd(op + 0, v * bf2f_lo(u0));
    atomicAdd(op + 1, v * bf2f_hi(u0));
    atomicAdd(op + 2, v * bf2f_lo(u1));
    atomicAdd(op + 3, v * bf2f_hi(u1));
}

// ---------------------------------------------------------------- launch
static inline size_t align16(size_t x) { return (x + 15) & ~(size_t)15; }

extern "C" void kernel_launch(void* const* d_in, const int* in_sizes, int n_in,
                              void* d_out, int out_size, void* d_ws, size_t ws_size,
                              hipStream_t stream) {
    const float* x    = (const float*)d_in[0];
    const int*   rows = (const int*)  d_in[1];
    const int*   cols = (const int*)  d_in[2];
    const float* vals = (const float*)d_in[3];
    const float* W    = (const float*)d_in[4];
    const float* b    = (const float*)d_in[5];
    float*       out  = (float*)d_out;

    const int n_nodes = in_sizes[0] / D;   // 50000
    const int n_edges = in_sizes[1];       // 800000
    const int nbuck   = (n_nodes + NB - 1) / NB;        // 1563
    const int histBlocks = (n_edges + 255) / 256;       // 3125
    const int convBlocks = (D * D + 255) / 256;         // 64
    const int gemmBlocks = (n_nodes + 63) / 64;         // 782

    // ---- workspace layout (16B-aligned regions)
    char*  base    = (char*)d_ws;
    size_t off     = 0;
    unsigned short* Wb = (unsigned short*)(base + off); off = align16(off + (size_t)D * D * 2);
    unsigned short* hb = (unsigned short*)(base + off); off = align16(off + (size_t)n_nodes * D * 2);
    int*   bcounts = (int*)  (base + off); off = align16(off + (size_t)nbuck * 4);
    int*   boffs   = (int*)  (base + off); off = align16(off + ((size_t)nbuck + 1) * 4);
    int*   bcursor = (int*)  (base + off); off = align16(off + (size_t)nbuck * 4);
    int2*  evec    = (int2*) (base + off); off = align16(off + (size_t)n_edges * 8);
    const bool bucket_ok = (off <= ws_size) && (n_nodes <= 65536) && (nbuck <= 2048);

    if (bucket_ok) {
        hipMemsetAsync(bcounts, 0, (size_t)nbuck * 4, stream);
        fused_pre<<<histBlocks + convBlocks, 256, 0, stream>>>(
            rows, bcounts, n_edges, W, Wb, histBlocks);
        scan_buckets<<<1, 1024, 0, stream>>>(bcounts, boffs, bcursor, nbuck);
        fused_main<<<2 * gemmBlocks, 256, 0, stream>>>(
            rows, cols, vals, bcursor, evec, n_edges, gemmBlocks,
            x, Wb, b, hb, n_nodes);
        aggregate_lds<<<nbuck, 256, 0, stream>>>(boffs, evec, hb, out, n_nodes);
    } else {
        // fallback: plain atomic scatter (correct for any size, slower)
        size_t off2 = 0;
        unsigned short* Wb2 = (unsigned short*)(base + off2); off2 = align16(off2 + (size_t)D * D * 2);
        unsigned short* hb2 = (unsigned short*)(base + off2); off2 = align16(off2 + (size_t)n_nodes * D * 2);
        convert_W<<<convBlocks, 256, 0, stream>>>(W, Wb2);
        gemm_mfma<<<gemmBlocks, 256, 0, stream>>>(x, Wb2, b, hb2, n_nodes);
        hipMemsetAsync(d_out, 0, (size_t)n_nodes * D * sizeof(float), stream);
        long long scatter_threads = (long long)n_edges * 32;
        int scatter_blocks = (int)((scatter_threads + 255) / 256);
        scatter_add<<<scatter_blocks, 256, 0, stream>>>(rows, cols, vals, hb2, out, n_edges);
    }
}

// Round 10
// 172.645 us; speedup vs baseline: 4.9435x; 4.9435x over previous
//
#include <hip/hip_runtime.h>

#define D 128
#define SCAN_BLK 256
#define SCAN_THREADS 1024

typedef short  bf16x8 __attribute__((ext_vector_type(8)));
typedef float  f32x4  __attribute__((ext_vector_type(4)));

// round-to-nearest-even float -> bf16 bits
static __device__ __forceinline__ unsigned short f2bf(float f) {
    unsigned u = __float_as_uint(f);
    u += 0x7FFFu + ((u >> 16) & 1u);
    return (unsigned short)(u >> 16);
}
static __device__ __forceinline__ float bf2f_lo(unsigned u) {
    return __uint_as_float((u & 0xFFFFu) << 16);
}
static __device__ __forceinline__ float bf2f_hi(unsigned u) {
    return __uint_as_float(u & 0xFFFF0000u);
}

// ------------------------------------------------ fused: hist_rows + convert_W
__global__ __launch_bounds__(256) void fused_pre(
    const int* __restrict__ rows, int* __restrict__ counts, int n_edges,
    const float* __restrict__ W, unsigned short* __restrict__ Wb, int histBlocks) {
    int bid = blockIdx.x;
    if (bid < histBlocks) {
        int i = bid * 256 + threadIdx.x;
        if (i < n_edges) atomicAdd(&counts[rows[i]], 1);
    } else {
        int i = (bid - histBlocks) * 256 + threadIdx.x;
        if (i < D * D) Wb[i] = f2bf(W[i]);
    }
}

// ------------------------------------------------ fused: permute + MFMA GEMM
// Groups of 5 blocks = 2 gemm + 3 grid-stride permute slots, co-resident for
// the whole kernel (R8-proven interleave). Permute writes 4-BYTE edge ids:
// 50k write frontiers x 64B lines = 3.2 MB -> fits per-XCD L2, killing the
// line-granular write amplification that 8B records caused (52 MB -> ~6 MB).
__global__ __launch_bounds__(256, 4) void fused_main(
    const int* __restrict__ rows, int* __restrict__ cursor,
    int* __restrict__ eidx, int n_edges, int permSlots,
    const float* __restrict__ x, const unsigned short* __restrict__ Wb,
    const float* __restrict__ b, unsigned short* __restrict__ hb, int n_rows) {
    const int bid = blockIdx.x;
    const int g   = bid / 5;
    const int r5  = bid % 5;

    if (r5 >= 2) {
        // ---- permute slot: grid-stride over edges, per-node cursors (16
        // atomics/address avg -> no same-address RMW chains; R9 lesson).
        const int slot   = g * 3 + (r5 - 2);
        const int stride = permSlots * 256;
        for (int i = slot * 256 + threadIdx.x; i < n_edges; i += stride) {
            int rr  = rows[i];
            int pos = atomicAdd(&cursor[rr], 1);
            eidx[pos] = i;
        }
        return;
    }

    // ---- gemm slot: h[m][o] = sum_k x[m][k]*W[o][k] + b[o] -> bf16
    const int gb   = g * 2 + r5;
    const int lane = threadIdx.x & 63;
    const int wv   = threadIdx.x >> 6;
    const int row0 = gb * 64 + wv * 16;
    if (row0 >= n_rows) return;               // no __syncthreads in this path
    const int m  = lane & 15;
    const int kg = lane >> 4;                 // 0..3

    int arow = row0 + m;
    if (arow >= n_rows) arow = n_rows - 1;    // clamp: loads valid, stores predicated
    const float* xr = x + (size_t)arow * D + kg * 8;

    // Load all x fragments first (independent), then convert, then MFMA.
    float4 xf[8];
#pragma unroll
    for (int ks = 0; ks < 4; ++ks) {
        xf[2 * ks]     = *(const float4*)(xr + ks * 32);
        xf[2 * ks + 1] = *(const float4*)(xr + ks * 32 + 4);
    }
    bf16x8 afr[4];
#pragma unroll
    for (int ks = 0; ks < 4; ++ks) {
        float4 f0 = xf[2 * ks], f1 = xf[2 * ks + 1];
        bf16x8 a;
        a[0] = (short)f2bf(f0.x); a[1] = (short)f2bf(f0.y);
        a[2] = (short)f2bf(f0.z); a[3] = (short)f2bf(f0.w);
        a[4] = (short)f2bf(f1.x); a[5] = (short)f2bf(f1.y);
        a[6] = (short)f2bf(f1.z); a[7] = (short)f2bf(f1.w);
        afr[ks] = a;
    }

    f32x4 acc[8];
#pragma unroll
    for (int n = 0; n < 8; ++n) acc[n] = (f32x4){0.f, 0.f, 0.f, 0.f};

#pragma unroll
    for (int ks = 0; ks < 4; ++ks) {
#pragma unroll
        for (int n = 0; n < 8; ++n) {
            bf16x8 bf = *(const bf16x8*)&Wb[(size_t)(n * 16 + m) * D + ks * 32 + kg * 8];
            acc[n] = __builtin_amdgcn_mfma_f32_16x16x32_bf16(afr[ks], bf, acc[n], 0, 0, 0);
        }
    }

#pragma unroll
    for (int n = 0; n < 8; ++n) {
        int col = n * 16 + m;
        float bc = b[col];
#pragma unroll
        for (int j = 0; j < 4; ++j) {
            int rr = row0 + kg * 4 + j;
            if (rr < n_rows) hb[(size_t)rr * D + col] = f2bf(acc[n][j] + bc);
        }
    }
}

// ---------------------------------------------------------------- scan chain
__global__ __launch_bounds__(SCAN_BLK) void scan_local(
    const int* __restrict__ counts, int* __restrict__ offs,
    int* __restrict__ blockSums, int n) {
    __shared__ int sh[SCAN_BLK];
    const int t = threadIdx.x;
    const int i = blockIdx.x * SCAN_BLK + t;
    int v = (i < n) ? counts[i] : 0;
    sh[t] = v;
    __syncthreads();
    for (int off = 1; off < SCAN_BLK; off <<= 1) {
        int add = (t >= off) ? sh[t - off] : 0;
        __syncthreads();
        sh[t] += add;
        __syncthreads();
    }
    if (i < n) offs[i] = sh[t] - v;
    if (t == SCAN_BLK - 1) blockSums[blockIdx.x] = sh[SCAN_BLK - 1];
}

__global__ __launch_bounds__(1024) void scan_blocks(
    int* __restrict__ blockSums, int* __restrict__ total, int nb) {
    __shared__ int sh[1024];
    const int t = threadIdx.x;
    int v = (t < nb) ? blockSums[t] : 0;
    sh[t] = v;
    __syncthreads();
    for (int off = 1; off < 1024; off <<= 1) {
        int add = (t >= off) ? sh[t - off] : 0;
        __syncthreads();
        sh[t] += add;
        __syncthreads();
    }
    if (t < nb) blockSums[t] = sh[t] - v;
    if (t == 1023) *total = sh[1023];
}

__global__ __launch_bounds__(SCAN_BLK) void scan_add(
    int* __restrict__ offs, int* __restrict__ cursor,
    const int* __restrict__ blockSums, int n) {
    const int i = blockIdx.x * SCAN_BLK + threadIdx.x;
    if (i < n) {
        int o = offs[i] + blockSums[blockIdx.x];
        offs[i]   = o;
        cursor[i] = o;
    }
}

__global__ __launch_bounds__(SCAN_THREADS) void scan_counts(
    const int* __restrict__ counts, int* __restrict__ offs,
    int* __restrict__ cursor, int n) {
    __shared__ int part[SCAN_THREADS];
    const int t = threadIdx.x;
    const int chunk = (n + SCAN_THREADS - 1) / SCAN_THREADS;
    const int s = t * chunk;
    const int e = min(s + chunk, n);
    int sum = 0;
    for (int i = s; i < e; ++i) sum += counts[i];
    part[t] = sum;
    __syncthreads();
    for (int off = 1; off < SCAN_THREADS; off <<= 1) {
        int add = (t >= off) ? part[t - off] : 0;
        __syncthreads();
        part[t] += add;
        __syncthreads();
    }
    int run = part[t] - sum;
    for (int i = s; i < e; ++i) {
        offs[i]   = run;
        cursor[i] = run;
        run += counts[i];
    }
    if (e == n) offs[n] = run;
}

// ---------------------------------------------------------------- aggregate
// One wave per node; lane owns 2 cols (4 B of bf16 h per gather).
// Records are 4 B edge ids; col/val re-fetched as broadcast loads from the
// L2/L3-resident cols/vals arrays. 8 records in flight per iteration.
// launch_bounds(256,4): allow up to 128 VGPR so the 8-deep gather unroll
// actually gets registers (R6/R8 compiled at VGPR=12 -> serialized loads).
__global__ __launch_bounds__(256, 4) void aggregate(
    const int* __restrict__ offs, const int* __restrict__ eidx,
    const int* __restrict__ cols, const float* __restrict__ vals,
    const unsigned short* __restrict__ hb, float* __restrict__ out, int n_nodes) {
    int wid = blockIdx.x * 4 + (threadIdx.x >> 6);
    if (wid >= n_nodes) return;
    int lane = threadIdx.x & 63;

    const int s = offs[wid];
    const int e = offs[wid + 1];
    const int c0 = lane * 2;
    float2 acc = make_float2(0.f, 0.f);

    int k = s;
    // peel to 4-alignment so int4 loads of eidx are 16B-aligned
    while ((k & 3) && k < e) {
        int   eid = eidx[k];
        int   c   = cols[eid];
        float v   = vals[eid];
        unsigned u = *(const unsigned*)&hb[(size_t)c * D + c0];
        acc.x += v * bf2f_lo(u); acc.y += v * bf2f_hi(u);
        ++k;
    }
    for (; k + 7 < e; k += 8) {
        int4 a0 = *(const int4*)&eidx[k];
        int4 a1 = *(const int4*)&eidx[k + 4];
        int ci0 = cols[a0.x], ci1 = cols[a0.y], ci2 = cols[a0.z], ci3 = cols[a0.w];
        int ci4 = cols[a1.x], ci5 = cols[a1.y], ci6 = cols[a1.z], ci7 = cols[a1.w];
        float v0 = vals[a0.x], v1 = vals[a0.y], v2 = vals[a0.z], v3 = vals[a0.w];
        float v4 = vals[a1.x], v5 = vals[a1.y], v6 = vals[a1.z], v7 = vals[a1.w];
        unsigned u0 = *(const unsigned*)&hb[(size_t)ci0 * D + c0];
        unsigned u1 = *(const unsigned*)&hb[(size_t)ci1 * D + c0];
        unsigned u2 = *(const unsigned*)&hb[(size_t)ci2 * D + c0];
        unsigned u3 = *(const unsigned*)&hb[(size_t)ci3 * D + c0];
        unsigned u4 = *(const unsigned*)&hb[(size_t)ci4 * D + c0];
        unsigned u5 = *(const unsigned*)&hb[(size_t)ci5 * D + c0];
        unsigned u6 = *(const unsigned*)&hb[(size_t)ci6 * D + c0];
        unsigned u7 = *(const unsigned*)&hb[(size_t)ci7 * D + c0];
        acc.x += v0 * bf2f_lo(u0); acc.y += v0 * bf2f_hi(u0);
        acc.x += v1 * bf2f_lo(u1); acc.y += v1 * bf2f_hi(u1);
        acc.x += v2 * bf2f_lo(u2); acc.y += v2 * bf2f_hi(u2);
        acc.x += v3 * bf2f_lo(u3); acc.y += v3 * bf2f_hi(u3);
        acc.x += v4 * bf2f_lo(u4); acc.y += v4 * bf2f_hi(u4);
        acc.x += v5 * bf2f_lo(u5); acc.y += v5 * bf2f_hi(u5);
        acc.x += v6 * bf2f_lo(u6); acc.y += v6 * bf2f_hi(u6);
        acc.x += v7 * bf2f_lo(u7); acc.y += v7 * bf2f_hi(u7);
    }
    for (; k < e; ++k) {
        int   eid = eidx[k];
        int   c   = cols[eid];
        float v   = vals[eid];
        unsigned u = *(const unsigned*)&hb[(size_t)c * D + c0];
        acc.x += v * bf2f_lo(u); acc.y += v * bf2f_hi(u);
    }

    *(float2*)&out[(size_t)wid * D + c0] = acc;
}

// ---------------------------------------------------------------- fallback
__global__ void convert_W(const float* __restrict__ W, unsigned short* __restrict__ Wb) {
    int i = blockIdx.x * blockDim.x + threadIdx.x;
    if (i < D * D) Wb[i] = f2bf(W[i]);
}

__global__ __launch_bounds__(256) void gemm_mfma(
    const float* __restrict__ x, const unsigned short* __restrict__ Wb,
    const float* __restrict__ b, unsigned short* __restrict__ hb, int n_rows) {
    const int lane = threadIdx.x & 63;
    const int wv   = threadIdx.x >> 6;
    const int row0 = blockIdx.x * 64 + wv * 16;
    if (row0 >= n_rows) return;
    const int m  = lane & 15;
    const int kg = lane >> 4;
    int arow = row0 + m;
    if (arow >= n_rows) arow = n_rows - 1;
    const float* xr = x + (size_t)arow * D + kg * 8;
    f32x4 acc[8];
#pragma unroll
    for (int n = 0; n < 8; ++n) acc[n] = (f32x4){0.f, 0.f, 0.f, 0.f};
#pragma unroll
    for (int ks = 0; ks < 4; ++ks) {
        float4 f0 = *(const float4*)(xr + ks * 32);
        float4 f1 = *(const float4*)(xr + ks * 32 + 4);
        bf16x8 a;
        a[0] = (short)f2bf(f0.x); a[1] = (short)f2bf(f0.y);
        a[2] = (short)f2bf(f0.z); a[3] = (short)f2bf(f0.w);
        a[4] = (short)f2bf(f1.x); a[5] = (short)f2bf(f1.y);
        a[6] = (short)f2bf(f1.z); a[7] = (short)f2bf(f1.w);
#pragma unroll
        for (int n = 0; n < 8; ++n) {
            bf16x8 bf = *(const bf16x8*)&Wb[(size_t)(n * 16 + m) * D + ks * 32 + kg * 8];
            acc[n] = __builtin_amdgcn_mfma_f32_16x16x32_bf16(a, bf, acc[n], 0, 0, 0);
        }
    }
#pragma unroll
    for (int n = 0; n < 8; ++n) {
        int col = n * 16 + m;
        float bc = b[col];
#pragma unroll
        for (int j = 0; j < 4; ++j) {
            int r = row0 + kg * 4 + j;
            if (r < n_rows) hb[(size_t)r * D + col] = f2bf(acc[n][j] + bc);
        }
    }
}

__global__ __launch_bounds__(256) void scatter_add(
    const int* __restrict__ rows, const int* __restrict__ cols,
    const float* __restrict__ vals, const unsigned short* __restrict__ hb,
    float* __restrict__ out, int n_edges) {
    long long gid = (long long)blockIdx.x * blockDim.x + threadIdx.x;
    int e  = (int)(gid >> 5);
    if (e >= n_edges) return;
    int d4 = ((int)gid & 31) * 4;
    int   r = rows[e];
    int   c = cols[e];
    float v = vals[e];
    const unsigned short* hp = &hb[(size_t)c * D + d4];
    unsigned u0 = *(const unsigned*)(hp + 0);
    unsigned u1 = *(const unsigned*)(hp + 2);
    float* op = &out[(size_t)r * D + d4];
    atomicAdd(op + 0, v * bf2f_lo(u0));
    atomicAdd(op + 1, v * bf2f_hi(u0));
    atomicAdd(op + 2, v * bf2f_lo(u1));
    atomicAdd(op + 3, v * bf2f_hi(u1));
}

// ---------------------------------------------------------------- launch
static inline size_t align16(size_t x) { return (x + 15) & ~(size_t)15; }

extern "C" void kernel_launch(void* const* d_in, const int* in_sizes, int n_in,
                              void* d_out, int out_size, void* d_ws, size_t ws_size,
                              hipStream_t stream) {
    const float* x    = (const float*)d_in[0];
    const int*   rows = (const int*)  d_in[1];
    const int*   cols = (const int*)  d_in[2];
    const float* vals = (const float*)d_in[3];
    const float* W    = (const float*)d_in[4];
    const float* b    = (const float*)d_in[5];
    float*       out  = (float*)d_out;

    const int n_nodes = in_sizes[0] / D;   // 50000
    const int n_edges = in_sizes[1];       // 800000
    const int nScanBlocks = (n_nodes + SCAN_BLK - 1) / SCAN_BLK;
    const int histBlocks  = (n_edges + 255) / 256;
    const int convBlocks  = (D * D + 255) / 256;
    const int gemmBlocks  = (n_nodes + 63) / 64;           // 782
    const int nGroups     = (gemmBlocks + 1) / 2;          // 391
    const int permSlots   = nGroups * 3;                   // 1173
    const int mainBlocks  = nGroups * 5;

    // ---- workspace layout (16B-aligned regions)
    char*  base    = (char*)d_ws;
    size_t off     = 0;
    unsigned short* Wb = (unsigned short*)(base + off); off = align16(off + (size_t)D * D * 2);
    unsigned short* hb = (unsigned short*)(base + off); off = align16(off + (size_t)n_nodes * D * 2);
    int*   counts  = (int*)  (base + off); off = align16(off + (size_t)n_nodes * 4);
    int*   offs    = (int*)  (base + off); off = align16(off + ((size_t)n_nodes + 1) * 4);
    int*   cursor  = (int*)  (base + off); off = align16(off + (size_t)n_nodes * 4);
    int*   bsums   = (int*)  (base + off); off = align16(off + (size_t)1024 * 4);
    int*   eidx    = (int*)  (base + off); off = align16(off + (size_t)n_edges * 4);
    const bool csr_fits = (off <= ws_size);

    if (csr_fits) {
        hipMemsetAsync(counts, 0, (size_t)n_nodes * 4, stream);
        fused_pre<<<histBlocks + convBlocks, 256, 0, stream>>>(
            rows, counts, n_edges, W, Wb, histBlocks);
        if (nScanBlocks <= 1024) {
            scan_local<<<nScanBlocks, SCAN_BLK, 0, stream>>>(counts, offs, bsums, n_nodes);
            scan_blocks<<<1, 1024, 0, stream>>>(bsums, &offs[n_nodes], nScanBlocks);
            scan_add<<<nScanBlocks, SCAN_BLK, 0, stream>>>(offs, cursor, bsums, n_nodes);
        } else {
            scan_counts<<<1, SCAN_THREADS, 0, stream>>>(counts, offs, cursor, n_nodes);
        }
        fused_main<<<mainBlocks, 256, 0, stream>>>(
            rows, cursor, eidx, n_edges, permSlots,
            x, Wb, b, hb, n_nodes);
        aggregate<<<(n_nodes + 3) / 4, 256, 0, stream>>>(
            offs, eidx, cols, vals, hb, out, n_nodes);
    } else {
        convert_W<<<convBlocks, 256, 0, stream>>>(W, Wb);
        gemm_mfma<<<gemmBlocks, 256, 0, stream>>>(x, Wb, b, hb, n_nodes);
        hipMemsetAsync(d_out, 0, (size_t)n_nodes * D * sizeof(float), stream);
        long long scatter_threads = (long long)n_edges * 32;
        int scatter_blocks = (int)((scatter_threads + 255) / 256);
        scatter_add<<<scatter_blocks, 256, 0, stream>>>(rows, cols, vals, hb, out, n_edges);
    }
}

// Round 11
// 141.589 us; speedup vs baseline: 6.0279x; 1.2193x over previous
//
#include <hip/hip_runtime.h>

#define D 128
#define SCAN_BLK 256
#define SCAN_THREADS 1024

typedef short  bf16x8 __attribute__((ext_vector_type(8)));
typedef float  f32x4  __attribute__((ext_vector_type(4)));

// round-to-nearest-even float -> bf16 bits
static __device__ __forceinline__ unsigned short f2bf(float f) {
    unsigned u = __float_as_uint(f);
    u += 0x7FFFu + ((u >> 16) & 1u);
    return (unsigned short)(u >> 16);
}
static __device__ __forceinline__ float bf2f_lo(unsigned u) {
    return __uint_as_float((u & 0xFFFFu) << 16);
}
static __device__ __forceinline__ float bf2f_hi(unsigned u) {
    return __uint_as_float(u & 0xFFFF0000u);
}

// ------------------------------------------------ fused: hist_rows + convert_W
__global__ __launch_bounds__(256) void fused_pre(
    const int* __restrict__ rows, int* __restrict__ counts, int n_edges,
    const float* __restrict__ W, unsigned short* __restrict__ Wb, int histBlocks) {
    int bid = blockIdx.x;
    if (bid < histBlocks) {
        int i = bid * 256 + threadIdx.x;
        if (i < n_edges) atomicAdd(&counts[rows[i]], 1);
    } else {
        int i = (bid - histBlocks) * 256 + threadIdx.x;
        if (i < D * D) Wb[i] = f2bf(W[i]);
    }
}

// ------------------------------------------------ fused: permute + MFMA GEMM
// R8-proven: groups of 5 blocks = 2 gemm + 3 grid-stride permute slots,
// co-resident for the whole kernel. 8B {col,val} records (R10 lesson: 4B
// edge-id records don't cut write-amp — partial-line-per-XCD effect — and
// the extra cols/vals indirection slows aggregate).
__global__ __launch_bounds__(256) void fused_main(
    const int* __restrict__ rows, const int* __restrict__ cols,
    const float* __restrict__ vals, int* __restrict__ cursor,
    int2* __restrict__ evec, int n_edges, int permSlots,
    const float* __restrict__ x, const unsigned short* __restrict__ Wb,
    const float* __restrict__ b, unsigned short* __restrict__ hb, int n_rows) {
    const int bid = blockIdx.x;
    const int g   = bid / 5;
    const int r5  = bid % 5;

    if (r5 >= 2) {
        // ---- permute slot: grid-stride over edges, per-node cursors
        // (16 atomics/address avg -> no same-address RMW chains; R9 lesson).
        const int slot   = g * 3 + (r5 - 2);
        const int stride = permSlots * 256;
        for (int i = slot * 256 + threadIdx.x; i < n_edges; i += stride) {
            int rr  = rows[i];
            int pos = atomicAdd(&cursor[rr], 1);
            evec[pos] = make_int2(cols[i], __float_as_int(vals[i]));
        }
        return;
    }

    // ---- gemm slot: h[m][o] = sum_k x[m][k]*W[o][k] + b[o] -> bf16
    const int gb   = g * 2 + r5;
    const int lane = threadIdx.x & 63;
    const int wv   = threadIdx.x >> 6;
    const int row0 = gb * 64 + wv * 16;
    if (row0 >= n_rows) return;               // no __syncthreads in this path
    const int m  = lane & 15;
    const int kg = lane >> 4;                 // 0..3

    int arow = row0 + m;
    if (arow >= n_rows) arow = n_rows - 1;    // clamp: loads valid, stores predicated
    const float* xr = x + (size_t)arow * D + kg * 8;

    f32x4 acc[8];
#pragma unroll
    for (int n = 0; n < 8; ++n) acc[n] = (f32x4){0.f, 0.f, 0.f, 0.f};

#pragma unroll
    for (int ks = 0; ks < 4; ++ks) {
        float4 f0 = *(const float4*)(xr + ks * 32);
        float4 f1 = *(const float4*)(xr + ks * 32 + 4);
        bf16x8 a;
        a[0] = (short)f2bf(f0.x); a[1] = (short)f2bf(f0.y);
        a[2] = (short)f2bf(f0.z); a[3] = (short)f2bf(f0.w);
        a[4] = (short)f2bf(f1.x); a[5] = (short)f2bf(f1.y);
        a[6] = (short)f2bf(f1.z); a[7] = (short)f2bf(f1.w);
#pragma unroll
        for (int n = 0; n < 8; ++n) {
            bf16x8 bf = *(const bf16x8*)&Wb[(size_t)(n * 16 + m) * D + ks * 32 + kg * 8];
            acc[n] = __builtin_amdgcn_mfma_f32_16x16x32_bf16(a, bf, acc[n], 0, 0, 0);
        }
    }

#pragma unroll
    for (int n = 0; n < 8; ++n) {
        int col = n * 16 + m;
        float bc = b[col];
#pragma unroll
        for (int j = 0; j < 4; ++j) {
            int rr = row0 + kg * 4 + j;
            if (rr < n_rows) hb[(size_t)rr * D + col] = f2bf(acc[n][j] + bc);
        }
    }
}

// ---------------------------------------------------------------- scan chain
__global__ __launch_bounds__(SCAN_BLK) void scan_local(
    const int* __restrict__ counts, int* __restrict__ offs,
    int* __restrict__ blockSums, int n) {
    __shared__ int sh[SCAN_BLK];
    const int t = threadIdx.x;
    const int i = blockIdx.x * SCAN_BLK + t;
    int v = (i < n) ? counts[i] : 0;
    sh[t] = v;
    __syncthreads();
    for (int off = 1; off < SCAN_BLK; off <<= 1) {
        int add = (t >= off) ? sh[t - off] : 0;
        __syncthreads();
        sh[t] += add;
        __syncthreads();
    }
    if (i < n) offs[i] = sh[t] - v;
    if (t == SCAN_BLK - 1) blockSums[blockIdx.x] = sh[SCAN_BLK - 1];
}

__global__ __launch_bounds__(1024) void scan_blocks(
    int* __restrict__ blockSums, int* __restrict__ total, int nb) {
    __shared__ int sh[1024];
    const int t = threadIdx.x;
    int v = (t < nb) ? blockSums[t] : 0;
    sh[t] = v;
    __syncthreads();
    for (int off = 1; off < 1024; off <<= 1) {
        int add = (t >= off) ? sh[t - off] : 0;
        __syncthreads();
        sh[t] += add;
        __syncthreads();
    }
    if (t < nb) blockSums[t] = sh[t] - v;
    if (t == 1023) *total = sh[1023];
}

__global__ __launch_bounds__(SCAN_BLK) void scan_add(
    int* __restrict__ offs, int* __restrict__ cursor,
    const int* __restrict__ blockSums, int n) {
    const int i = blockIdx.x * SCAN_BLK + threadIdx.x;
    if (i < n) {
        int o = offs[i] + blockSums[blockIdx.x];
        offs[i]   = o;
        cursor[i] = o;
    }
}

__global__ __launch_bounds__(SCAN_THREADS) void scan_counts(
    const int* __restrict__ counts, int* __restrict__ offs,
    int* __restrict__ cursor, int n) {
    __shared__ int part[SCAN_THREADS];
    const int t = threadIdx.x;
    const int chunk = (n + SCAN_THREADS - 1) / SCAN_THREADS;
    const int s = t * chunk;
    const int e = min(s + chunk, n);
    int sum = 0;
    for (int i = s; i < e; ++i) sum += counts[i];
    part[t] = sum;
    __syncthreads();
    for (int off = 1; off < SCAN_THREADS; off <<= 1) {
        int add = (t >= off) ? part[t - off] : 0;
        __syncthreads();
        part[t] += add;
        __syncthreads();
    }
    int run = part[t] - sum;
    for (int i = s; i < e; ++i) {
        offs[i]   = run;
        cursor[i] = run;
        run += counts[i];
    }
    if (e == n) offs[n] = run;
}

// ---------------------------------------------------------------- aggregate
// One wave per node; lane owns 2 cols (4 B of bf16 h per gather).
// 8 records in flight per iteration (4x int4 broadcast evec loads + 8 gathers).
// __launch_bounds__(256,4): R8 compiled this at VGPR=12 which cannot hold
// 8 in-flight gathers -> compiler serialized the unroll. 128-VGPR budget
// (4 waves/SIMD, still 16 waves/CU) lets the MLP depth actually materialize.
__global__ __launch_bounds__(256, 4) void aggregate(
    const int* __restrict__ offs, const int2* __restrict__ evec,
    const unsigned short* __restrict__ hb, float* __restrict__ out, int n_nodes) {
    int wid = blockIdx.x * 4 + (threadIdx.x >> 6);
    if (wid >= n_nodes) return;
    int lane = threadIdx.x & 63;

    int s = offs[wid];
    int e = offs[wid + 1];
    const int c0 = lane * 2;
    float2 acc = make_float2(0.f, 0.f);

    int k = s;
    if ((k & 1) && k < e) {   // peel to even k -> 16B-aligned int4 loads
        int2 e0 = evec[k];
        unsigned u0 = *(const unsigned*)&hb[(size_t)e0.x * D + c0];
        float v0 = __int_as_float(e0.y);
        acc.x += v0 * bf2f_lo(u0); acc.y += v0 * bf2f_hi(u0);
        ++k;
    }
    for (; k + 7 < e; k += 8) {
        int4 p0 = *(const int4*)&evec[k];
        int4 p1 = *(const int4*)&evec[k + 2];
        int4 p2 = *(const int4*)&evec[k + 4];
        int4 p3 = *(const int4*)&evec[k + 6];
        unsigned u0 = *(const unsigned*)&hb[(size_t)p0.x * D + c0];
        unsigned u1 = *(const unsigned*)&hb[(size_t)p0.z * D + c0];
        unsigned u2 = *(const unsigned*)&hb[(size_t)p1.x * D + c0];
        unsigned u3 = *(const unsigned*)&hb[(size_t)p1.z * D + c0];
        unsigned u4 = *(const unsigned*)&hb[(size_t)p2.x * D + c0];
        unsigned u5 = *(const unsigned*)&hb[(size_t)p2.z * D + c0];
        unsigned u6 = *(const unsigned*)&hb[(size_t)p3.x * D + c0];
        unsigned u7 = *(const unsigned*)&hb[(size_t)p3.z * D + c0];
        float v0 = __int_as_float(p0.y), v1 = __int_as_float(p0.w);
        float v2 = __int_as_float(p1.y), v3 = __int_as_float(p1.w);
        float v4 = __int_as_float(p2.y), v5 = __int_as_float(p2.w);
        float v6 = __int_as_float(p3.y), v7 = __int_as_float(p3.w);
        acc.x += v0 * bf2f_lo(u0); acc.y += v0 * bf2f_hi(u0);
        acc.x += v1 * bf2f_lo(u1); acc.y += v1 * bf2f_hi(u1);
        acc.x += v2 * bf2f_lo(u2); acc.y += v2 * bf2f_hi(u2);
        acc.x += v3 * bf2f_lo(u3); acc.y += v3 * bf2f_hi(u3);
        acc.x += v4 * bf2f_lo(u4); acc.y += v4 * bf2f_hi(u4);
        acc.x += v5 * bf2f_lo(u5); acc.y += v5 * bf2f_hi(u5);
        acc.x += v6 * bf2f_lo(u6); acc.y += v6 * bf2f_hi(u6);
        acc.x += v7 * bf2f_lo(u7); acc.y += v7 * bf2f_hi(u7);
    }
    for (; k + 1 < e; k += 2) {
        int4 p0 = *(const int4*)&evec[k];
        unsigned u0 = *(const unsigned*)&hb[(size_t)p0.x * D + c0];
        unsigned u1 = *(const unsigned*)&hb[(size_t)p0.z * D + c0];
        float v0 = __int_as_float(p0.y), v1 = __int_as_float(p0.w);
        acc.x += v0 * bf2f_lo(u0); acc.y += v0 * bf2f_hi(u0);
        acc.x += v1 * bf2f_lo(u1); acc.y += v1 * bf2f_hi(u1);
    }
    if (k < e) {
        int2 e0 = evec[k];
        unsigned u0 = *(const unsigned*)&hb[(size_t)e0.x * D + c0];
        float v0 = __int_as_float(e0.y);
        acc.x += v0 * bf2f_lo(u0); acc.y += v0 * bf2f_hi(u0);
    }

    *(float2*)&out[(size_t)wid * D + c0] = acc;
}

// ---------------------------------------------------------------- fallback
__global__ __launch_bounds__(256) void scatter_add(
    const int* __restrict__ rows, const int* __restrict__ cols,
    const float* __restrict__ vals, const unsigned short* __restrict__ hb,
    float* __restrict__ out, int n_edges) {
    long long gid = (long long)blockIdx.x * blockDim.x + threadIdx.x;
    int e  = (int)(gid >> 5);
    if (e >= n_edges) return;
    int d4 = ((int)gid & 31) * 4;
    int   r = rows[e];
    int   c = cols[e];
    float v = vals[e];
    const unsigned short* hp = &hb[(size_t)c * D + d4];
    unsigned u0 = *(const unsigned*)(hp + 0);
    unsigned u1 = *(const unsigned*)(hp + 2);
    float* op = &out[(size_t)r * D + d4];
    atomicAdd(op + 0, v * bf2f_lo(u0));
    atomicAdd(op + 1, v * bf2f_hi(u0));
    atomicAdd(op + 2, v * bf2f_lo(u1));
    atomicAdd(op + 3, v * bf2f_hi(u1));
}

__global__ void convert_W(const float* __restrict__ W, unsigned short* __restrict__ Wb) {
    int i = blockIdx.x * blockDim.x + threadIdx.x;
    if (i < D * D) Wb[i] = f2bf(W[i]);
}

__global__ __launch_bounds__(256) void gemm_mfma(
    const float* __restrict__ x, const unsigned short* __restrict__ Wb,
    const float* __restrict__ b, unsigned short* __restrict__ hb, int n_rows) {
    const int lane = threadIdx.x & 63;
    const int wv   = threadIdx.x >> 6;
    const int row0 = blockIdx.x * 64 + wv * 16;
    if (row0 >= n_rows) return;
    const int m  = lane & 15;
    const int kg = lane >> 4;
    int arow = row0 + m;
    if (arow >= n_rows) arow = n_rows - 1;
    const float* xr = x + (size_t)arow * D + kg * 8;
    f32x4 acc[8];
#pragma unroll
    for (int n = 0; n < 8; ++n) acc[n] = (f32x4){0.f, 0.f, 0.f, 0.f};
#pragma unroll
    for (int ks = 0; ks < 4; ++ks) {
        float4 f0 = *(const float4*)(xr + ks * 32);
        float4 f1 = *(const float4*)(xr + ks * 32 + 4);
        bf16x8 a;
        a[0] = (short)f2bf(f0.x); a[1] = (short)f2bf(f0.y);
        a[2] = (short)f2bf(f0.z); a[3] = (short)f2bf(f0.w);
        a[4] = (short)f2bf(f1.x); a[5] = (short)f2bf(f1.y);
        a[6] = (short)f2bf(f1.z); a[7] = (short)f2bf(f1.w);
#pragma unroll
        for (int n = 0; n < 8; ++n) {
            bf16x8 bf = *(const bf16x8*)&Wb[(size_t)(n * 16 + m) * D + ks * 32 + kg * 8];
            acc[n] = __builtin_amdgcn_mfma_f32_16x16x32_bf16(a, bf, acc[n], 0, 0, 0);
        }
    }
#pragma unroll
    for (int n = 0; n < 8; ++n) {
        int col = n * 16 + m;
        float bc = b[col];
#pragma unroll
        for (int j = 0; j < 4; ++j) {
            int r = row0 + kg * 4 + j;
            if (r < n_rows) hb[(size_t)r * D + col] = f2bf(acc[n][j] + bc);
        }
    }
}

// ---------------------------------------------------------------- launch
static inline size_t align16(size_t x) { return (x + 15) & ~(size_t)15; }

extern "C" void kernel_launch(void* const* d_in, const int* in_sizes, int n_in,
                              void* d_out, int out_size, void* d_ws, size_t ws_size,
                              hipStream_t stream) {
    const float* x    = (const float*)d_in[0];
    const int*   rows = (const int*)  d_in[1];
    const int*   cols = (const int*)  d_in[2];
    const float* vals = (const float*)d_in[3];
    const float* W    = (const float*)d_in[4];
    const float* b    = (const float*)d_in[5];
    float*       out  = (float*)d_out;

    const int n_nodes = in_sizes[0] / D;   // 50000
    const int n_edges = in_sizes[1];       // 800000
    const int nScanBlocks = (n_nodes + SCAN_BLK - 1) / SCAN_BLK;
    const int histBlocks  = (n_edges + 255) / 256;
    const int convBlocks  = (D * D + 255) / 256;
    const int gemmBlocks  = (n_nodes + 63) / 64;           // 782
    const int nGroups     = (gemmBlocks + 1) / 2;          // 391
    const int permSlots   = nGroups * 3;                   // 1173
    const int mainBlocks  = nGroups * 5;

    // ---- workspace layout (16B-aligned regions)
    char*  base    = (char*)d_ws;
    size_t off     = 0;
    unsigned short* Wb = (unsigned short*)(base + off); off = align16(off + (size_t)D * D * 2);
    unsigned short* hb = (unsigned short*)(base + off); off = align16(off + (size_t)n_nodes * D * 2);
    int*   counts  = (int*)  (base + off); off = align16(off + (size_t)n_nodes * 4);
    int*   offs    = (int*)  (base + off); off = align16(off + ((size_t)n_nodes + 1) * 4);
    int*   cursor  = (int*)  (base + off); off = align16(off + (size_t)n_nodes * 4);
    int*   bsums   = (int*)  (base + off); off = align16(off + (size_t)1024 * 4);
    int2*  evec    = (int2*) (base + off); off = align16(off + (size_t)n_edges * 8);
    const bool csr_fits = (off <= ws_size);

    if (csr_fits) {
        hipMemsetAsync(counts, 0, (size_t)n_nodes * 4, stream);
        fused_pre<<<histBlocks + convBlocks, 256, 0, stream>>>(
            rows, counts, n_edges, W, Wb, histBlocks);
        if (nScanBlocks <= 1024) {
            scan_local<<<nScanBlocks, SCAN_BLK, 0, stream>>>(counts, offs, bsums, n_nodes);
            scan_blocks<<<1, 1024, 0, stream>>>(bsums, &offs[n_nodes], nScanBlocks);
            scan_add<<<nScanBlocks, SCAN_BLK, 0, stream>>>(offs, cursor, bsums, n_nodes);
        } else {
            scan_counts<<<1, SCAN_THREADS, 0, stream>>>(counts, offs, cursor, n_nodes);
        }
        fused_main<<<mainBlocks, 256, 0, stream>>>(
            rows, cols, vals, cursor, evec, n_edges, permSlots,
            x, Wb, b, hb, n_nodes);
        aggregate<<<(n_nodes + 3) / 4, 256, 0, stream>>>(offs, evec, hb, out, n_nodes);
    } else {
        convert_W<<<convBlocks, 256, 0, stream>>>(W, Wb);
        gemm_mfma<<<gemmBlocks, 256, 0, stream>>>(x, Wb, b, hb, n_nodes);
        hipMemsetAsync(d_out, 0, (size_t)n_nodes * D * sizeof(float), stream);
        long long scatter_threads = (long long)n_edges * 32;
        int scatter_blocks = (int)((scatter_threads + 255) / 256);
        scatter_add<<<scatter_blocks, 256, 0, stream>>>(rows, cols, vals, hb, out, n_edges);
    }
}